// Round 5
// baseline (77.692 us; speedup 1.0000x reference)
//
#include <hip/hip_runtime.h>

#define NROWS  65536
#define NCLS   256
#define NBLK   2048
#define NLINE  64              // partial-sum cachelines; NBLK/NLINE = 32 blocks each

// Device-global finish state. Zero at module load; every call leaves it zero
// again => deterministic across calls, immune to harness d_ws poisoning.
struct __align__(64) PartLine { float v; int cnt; int pad[14]; };
__device__ PartLine g_line[NLINE];
__device__ int      g_master;

__global__ __launch_bounds__(256) void OrdinalLoss_main_kernel(
    const float* __restrict__ pred, const int* __restrict__ tgt,
    float* __restrict__ out, int nrows)
{
    const int tid    = blockIdx.x * blockDim.x + threadIdx.x;
    const int lane   = threadIdx.x & 63;
    const int g      = lane >> 4;        // row within 4-row pack
    const int li     = lane & 15;        // lane within 16-lane row group
    const int wave   = tid >> 6;
    const int nwaves = (gridDim.x * blockDim.x) >> 6;

    float acc = 0.0f;

    // ---- distributed gather: 8 rows per wave via lanes 0..7 ----
    if (lane < 8) {
        for (int r = wave * 8 + lane; r < nrows; r += nwaves * 8)
            acc = -pred[(size_t)r * NCLS + tgt[r]];
    }

    // ---- main pass: 4 rows per wave, 16 lanes per row (R3 body, unchanged) ----
    const int npacks = nrows >> 2;
    for (int pack = wave; pack < npacks; pack += nwaves) {
        const int row = pack * 4 + g;
        const float* rp = pred + (size_t)row * NCLS + li * 4;

        const float4 p0 = *reinterpret_cast<const float4*>(rp);
        const float4 p1 = *reinterpret_cast<const float4*>(rp + 64);
        const float4 p2 = *reinterpret_cast<const float4*>(rp + 128);
        const float4 p3 = *reinterpret_cast<const float4*>(rp + 192);
        const float tf  = (float)tgt[row];
        const float j0  = (float)(li * 4);

        float s = 0.0f, w = 0.0f;
        #define TERM(pv, col) { float e = __expf(pv); s += e;              \
                                float d = (col) - tf; w = fmaf(e * d, d, w); }
        TERM(p0.x, j0 +   0.0f) TERM(p0.y, j0 +   1.0f)
        TERM(p0.z, j0 +   2.0f) TERM(p0.w, j0 +   3.0f)
        TERM(p1.x, j0 +  64.0f) TERM(p1.y, j0 +  65.0f)
        TERM(p1.z, j0 +  66.0f) TERM(p1.w, j0 +  67.0f)
        TERM(p2.x, j0 + 128.0f) TERM(p2.y, j0 + 129.0f)
        TERM(p2.z, j0 + 130.0f) TERM(p2.w, j0 + 131.0f)
        TERM(p3.x, j0 + 192.0f) TERM(p3.y, j0 + 193.0f)
        TERM(p3.z, j0 + 194.0f) TERM(p3.w, j0 + 195.0f)
        #undef TERM

        #pragma unroll
        for (int m = 8; m; m >>= 1) {
            s += __shfl_xor(s, m);
            w += __shfl_xor(w, m);
        }
        if (li == 0)
            acc += __logf(s) + w / s;
    }

    // ---- block reduce ----
    __shared__ float red[256];
    __shared__ int amLast;
    red[threadIdx.x] = acc;
    __syncthreads();
    float v = 0.0f;
    if (threadIdx.x < 64) {
        v = red[threadIdx.x] + red[threadIdx.x + 64] +
            red[threadIdx.x + 128] + red[threadIdx.x + 192];
        #pragma unroll
        for (int mask = 32; mask; mask >>= 1)
            v += __shfl_xor(v, mask);
    }

    // ---- fused finish: 64-line fan-in, last block reduces & resets ----
    if (threadIdx.x == 0) {
        amLast = 0;
        const int ln = blockIdx.x & (NLINE - 1);
        atomicAdd(&g_line[ln].v, v * (1.0f / (float)NROWS));
        __threadfence();                         // v-add visible before cnt-add
        if (atomicAdd(&g_line[ln].cnt, 1) == (NBLK / NLINE) - 1) {
            if (atomicAdd(&g_master, 1) == NLINE - 1)
                amLast = 1;                      // this block is globally last
        }
    }
    __syncthreads();
    if (amLast) {
        __threadfence();                         // acquire all lines' v-adds
        if (threadIdx.x < NLINE) {
            float r = __hip_atomic_load(&g_line[threadIdx.x].v,
                                        __ATOMIC_RELAXED, __HIP_MEMORY_SCOPE_AGENT);
            #pragma unroll
            for (int mask = 32; mask; mask >>= 1)
                r += __shfl_xor(r, mask);
            if (threadIdx.x == 0)
                out[0] = r;
            // reset state to zero for the next call (read happened above)
            __hip_atomic_store(&g_line[threadIdx.x].v, 0.0f,
                               __ATOMIC_RELAXED, __HIP_MEMORY_SCOPE_AGENT);
            __hip_atomic_store(&g_line[threadIdx.x].cnt, 0,
                               __ATOMIC_RELAXED, __HIP_MEMORY_SCOPE_AGENT);
            if (threadIdx.x == 0)
                __hip_atomic_store(&g_master, 0,
                                   __ATOMIC_RELAXED, __HIP_MEMORY_SCOPE_AGENT);
        }
    }
}

extern "C" void kernel_launch(void* const* d_in, const int* in_sizes, int n_in,
                              void* d_out, int out_size, void* d_ws, size_t ws_size,
                              hipStream_t stream) {
    const float* pred = (const float*)d_in[0];
    const int*   tgt  = (const int*)d_in[1];
    float*       out  = (float*)d_out;
    const int nrows   = in_sizes[1];   // 65536 targets

    OrdinalLoss_main_kernel<<<NBLK, 256, 0, stream>>>(pred, tgt, out, nrows);
}

// Round 6
// 19.711 us; speedup vs baseline: 3.9415x; 3.9415x over previous
//
#include <hip/hip_runtime.h>

#define NROWS  65536
#define NCLS   256
#define NBLK   2048
#define NLINE  64              // partial-sum lines; NBLK/NLINE = 32 blocks each
#define BPL    (NBLK / NLINE)

// Device-global finish state. Zero at module load; every call resets it to
// zero => deterministic across graph replays, immune to d_ws poisoning.
// NO fences anywhere: ordering comes from completed returning atomics only.
struct __align__(128) Line { float v; int cnt; int pad[30]; };
__device__ Line g_line[NLINE];
__device__ int  g_master;

__global__ __launch_bounds__(256) void OrdinalLoss_main_kernel(
    const float* __restrict__ pred, const int* __restrict__ tgt,
    float* __restrict__ out, int nrows)
{
    const int tid    = blockIdx.x * blockDim.x + threadIdx.x;
    const int lane   = threadIdx.x & 63;
    const int g      = lane >> 4;        // row within 4-row pack
    const int li     = lane & 15;        // lane within 16-lane row group
    const int wave   = tid >> 6;
    const int nwaves = (gridDim.x * blockDim.x) >> 6;

    float acc = 0.0f;

    // ---- gather pass: -p[row][t[row]], one row per thread (R3 form) ----
    if (tid < nrows)
        acc = -pred[(size_t)tid * NCLS + tgt[tid]];

    // ---- main pass: 4 rows per wave, 16 lanes per row (R3 body, unchanged) ----
    const int npacks = nrows >> 2;
    for (int pack = wave; pack < npacks; pack += nwaves) {
        const int row = pack * 4 + g;
        const float* rp = pred + (size_t)row * NCLS + li * 4;

        const float4 p0 = *reinterpret_cast<const float4*>(rp);
        const float4 p1 = *reinterpret_cast<const float4*>(rp + 64);
        const float4 p2 = *reinterpret_cast<const float4*>(rp + 128);
        const float4 p3 = *reinterpret_cast<const float4*>(rp + 192);
        const float tf  = (float)tgt[row];
        const float j0  = (float)(li * 4);

        float s = 0.0f, w = 0.0f;
        #define TERM(pv, col) { float e = __expf(pv); s += e;              \
                                float d = (col) - tf; w = fmaf(e * d, d, w); }
        TERM(p0.x, j0 +   0.0f) TERM(p0.y, j0 +   1.0f)
        TERM(p0.z, j0 +   2.0f) TERM(p0.w, j0 +   3.0f)
        TERM(p1.x, j0 +  64.0f) TERM(p1.y, j0 +  65.0f)
        TERM(p1.z, j0 +  66.0f) TERM(p1.w, j0 +  67.0f)
        TERM(p2.x, j0 + 128.0f) TERM(p2.y, j0 + 129.0f)
        TERM(p2.z, j0 + 130.0f) TERM(p2.w, j0 + 131.0f)
        TERM(p3.x, j0 + 192.0f) TERM(p3.y, j0 + 193.0f)
        TERM(p3.z, j0 + 194.0f) TERM(p3.w, j0 + 195.0f)
        #undef TERM

        #pragma unroll
        for (int m = 8; m; m >>= 1) {
            s += __shfl_xor(s, m);
            w += __shfl_xor(w, m);
        }
        if (li == 0)
            acc += __logf(s) + w / s;
    }

    // ---- block reduce ----
    __shared__ float red[256];
    __shared__ int amLast;
    red[threadIdx.x] = acc;
    __syncthreads();
    float v = 0.0f;
    if (threadIdx.x < 64) {
        v = red[threadIdx.x] + red[threadIdx.x + 64] +
            red[threadIdx.x + 128] + red[threadIdx.x + 192];
        #pragma unroll
        for (int mask = 32; mask; mask >>= 1)
            v += __shfl_xor(v, mask);
    }

    // ---- fence-free fused finish ----
    if (threadIdx.x == 0) {
        amLast = 0;
        const int ln = blockIdx.x & (NLINE - 1);
        // returning atomic: completion (value in register) == processed at
        // the coherence point. Fake-use forces s_waitcnt vmcnt(0) here,
        // so the counter atomic below ISSUES only after the add is done.
        float old = atomicAdd(&g_line[ln].v, v * (1.0f / (float)NROWS));
        asm volatile("" :: "v"(old));
        if (atomicAdd(&g_line[ln].cnt, 1) == BPL - 1) {
            // cnt==BPL-1 returned => all BPL v-adds of this line are done
            if (atomicAdd(&g_master, 1) == NLINE - 1)
                amLast = 1;              // all lines complete
        }
    }
    __syncthreads();
    if (amLast) {
        if (threadIdx.x < NLINE) {
            // agent-scope atomic loads: read at coherence point, bypass L1
            float r = __hip_atomic_load(&g_line[threadIdx.x].v,
                                        __ATOMIC_RELAXED, __HIP_MEMORY_SCOPE_AGENT);
            #pragma unroll
            for (int mask = 32; mask; mask >>= 1)
                r += __shfl_xor(r, mask);
            if (threadIdx.x == 0)
                out[0] = r;
            // reset state to zero for the next call
            __hip_atomic_store(&g_line[threadIdx.x].v, 0.0f,
                               __ATOMIC_RELAXED, __HIP_MEMORY_SCOPE_AGENT);
            __hip_atomic_store(&g_line[threadIdx.x].cnt, 0,
                               __ATOMIC_RELAXED, __HIP_MEMORY_SCOPE_AGENT);
            if (threadIdx.x == 0)
                __hip_atomic_store(&g_master, 0,
                                   __ATOMIC_RELAXED, __HIP_MEMORY_SCOPE_AGENT);
        }
    }
}

extern "C" void kernel_launch(void* const* d_in, const int* in_sizes, int n_in,
                              void* d_out, int out_size, void* d_ws, size_t ws_size,
                              hipStream_t stream) {
    const float* pred = (const float*)d_in[0];
    const int*   tgt  = (const int*)d_in[1];
    float*       out  = (float*)d_out;
    const int nrows   = in_sizes[1];   // 65536 targets

    OrdinalLoss_main_kernel<<<NBLK, 256, 0, stream>>>(pred, tgt, out, nrows);
}

// Round 7
// 18.868 us; speedup vs baseline: 4.1176x; 1.0447x over previous
//
#include <hip/hip_runtime.h>

#define NROWS  65536
#define NCLS   256
#define NBLK   2048
#define NLINE  64              // partial-sum lines; NBLK/NLINE = 32 blocks each
#define BPL    (NBLK / NLINE)

// Device-global finish state. Zero at module load; every call resets it to
// zero => deterministic across graph replays, immune to d_ws poisoning.
// NO fences: ordering comes from completed returning atomics only (R6-proven).
struct __align__(128) Line { float v; int cnt; int pad[30]; };
__device__ Line g_line[NLINE];
__device__ int  g_master;

__global__ __launch_bounds__(256) void OrdinalLoss_main_kernel(
    const float* __restrict__ pred, const int* __restrict__ tgt,
    float* __restrict__ out, int nrows)
{
    const int tid    = blockIdx.x * blockDim.x + threadIdx.x;
    const int lane   = threadIdx.x & 63;
    const int g      = lane >> 4;        // row within 4-row pack
    const int li     = lane & 15;        // lane within 16-lane row group
    const int wave   = tid >> 6;
    const int nwaves = (gridDim.x * blockDim.x) >> 6;

    float acc = 0.0f;

    // per-lane column constants: col(k) = li*4 + (k>>2)*64 + (k&3)
    const float j0 = (float)(li * 4);
    float c[16], c2[16];
    #pragma unroll
    for (int k = 0; k < 16; ++k) {
        const float col = j0 + (float)((k >> 2) * 64 + (k & 3));
        c[k]  = col;
        c2[k] = col * col;
    }

    const int npacks = nrows >> 2;
    for (int pack = wave; pack < npacks; pack += nwaves) {
        const int row = pack * 4 + g;
        const float* rp = pred + (size_t)row * NCLS + li * 4;

        const float4 a0 = *reinterpret_cast<const float4*>(rp);
        const float4 a1 = *reinterpret_cast<const float4*>(rp + 64);
        const float4 a2 = *reinterpret_cast<const float4*>(rp + 128);
        const float4 a3 = *reinterpret_cast<const float4*>(rp + 192);
        const int    t  = tgt[row];          // 16-lane broadcast, 1 line/wave

        // moments: s0=sum e, s1=sum e*j, s2=sum e*j^2 — independent of t
        float s0 = 0.0f, s1 = 0.0f, s2 = 0.0f;
        #define TERM(PV, K) { float e = __expf(PV); s0 += e;                \
                              s1 = fmaf(e, c[K],  s1);                      \
                              s2 = fmaf(e, c2[K], s2); }
        TERM(a0.x, 0)  TERM(a0.y, 1)  TERM(a0.z, 2)  TERM(a0.w, 3)
        TERM(a1.x, 4)  TERM(a1.y, 5)  TERM(a1.z, 6)  TERM(a1.w, 7)
        TERM(a2.x, 8)  TERM(a2.y, 9)  TERM(a2.z,10)  TERM(a2.w,11)
        TERM(a3.x,12)  TERM(a3.y,13)  TERM(a3.z,14)  TERM(a3.w,15)
        #undef TERM

        // in-register p[t] extraction: owning lane li==(t>>2)&15,
        // quad t>>6, component t&3. Static selects only (no runtime indexing).
        const int q  = t >> 6;
        const int r  = t & 3;
        const float4 Q = (q == 0) ? a0 : (q == 1) ? a1 : (q == 2) ? a2 : a3;
        const float pv = (r == 0) ? Q.x : (r == 1) ? Q.y : (r == 2) ? Q.z : Q.w;
        float pt = (li == ((t >> 2) & 15)) ? pv : 0.0f;

        // 16-lane reduce, 4 channels, masks 8/4/2/1 only
        #pragma unroll
        for (int m = 8; m; m >>= 1) {
            s0 += __shfl_xor(s0, m);
            s1 += __shfl_xor(s1, m);
            s2 += __shfl_xor(s2, m);
            pt += __shfl_xor(pt, m);
        }
        if (li == 0) {
            const float tf = (float)t;
            // row loss = (log s0 - p_t) + (s2 - 2 t s1 + t^2 s0)/s0
            acc += __logf(s0) - pt
                 + (s2 - 2.0f * tf * s1 + tf * tf * s0) / s0;
        }
    }

    // ---- block reduce ----
    __shared__ float red[256];
    __shared__ int amLast;
    red[threadIdx.x] = acc;
    __syncthreads();
    float v = 0.0f;
    if (threadIdx.x < 64) {
        v = red[threadIdx.x] + red[threadIdx.x + 64] +
            red[threadIdx.x + 128] + red[threadIdx.x + 192];
        #pragma unroll
        for (int mask = 32; mask; mask >>= 1)
            v += __shfl_xor(v, mask);
    }

    // ---- fence-free fused finish (R6-proven) ----
    if (threadIdx.x == 0) {
        amLast = 0;
        const int ln = blockIdx.x & (NLINE - 1);
        float old = atomicAdd(&g_line[ln].v, v * (1.0f / (float)NROWS));
        asm volatile("" :: "v"(old));        // force vmcnt wait: add completed
        if (atomicAdd(&g_line[ln].cnt, 1) == BPL - 1) {
            if (atomicAdd(&g_master, 1) == NLINE - 1)
                amLast = 1;                  // all lines complete
        }
    }
    __syncthreads();
    if (amLast) {
        if (threadIdx.x < NLINE) {
            float r = __hip_atomic_load(&g_line[threadIdx.x].v,
                                        __ATOMIC_RELAXED, __HIP_MEMORY_SCOPE_AGENT);
            #pragma unroll
            for (int mask = 32; mask; mask >>= 1)
                r += __shfl_xor(r, mask);
            if (threadIdx.x == 0)
                out[0] = r;
            __hip_atomic_store(&g_line[threadIdx.x].v, 0.0f,
                               __ATOMIC_RELAXED, __HIP_MEMORY_SCOPE_AGENT);
            __hip_atomic_store(&g_line[threadIdx.x].cnt, 0,
                               __ATOMIC_RELAXED, __HIP_MEMORY_SCOPE_AGENT);
            if (threadIdx.x == 0)
                __hip_atomic_store(&g_master, 0,
                                   __ATOMIC_RELAXED, __HIP_MEMORY_SCOPE_AGENT);
        }
    }
}

extern "C" void kernel_launch(void* const* d_in, const int* in_sizes, int n_in,
                              void* d_out, int out_size, void* d_ws, size_t ws_size,
                              hipStream_t stream) {
    const float* pred = (const float*)d_in[0];
    const int*   tgt  = (const int*)d_in[1];
    float*       out  = (float*)d_out;
    const int nrows   = in_sizes[1];   // 65536 targets

    OrdinalLoss_main_kernel<<<NBLK, 256, 0, stream>>>(pred, tgt, out, nrows);
}

// Round 8
// 17.356 us; speedup vs baseline: 4.4763x; 1.0871x over previous
//
#include <hip/hip_runtime.h>

#define NROWS  65536
#define NCLS   256
#define NBLK   2048
#define NLINE  64              // partial-sum lines; NBLK/NLINE = 32 blocks each
#define BPL    (NBLK / NLINE)

typedef float nt_f4 __attribute__((ext_vector_type(4)));

// Device-global finish state. Zero at module load; every call resets it to
// zero => deterministic across graph replays, immune to d_ws poisoning.
// NO fences: ordering comes from completed returning atomics only (R6-proven).
struct __align__(128) Line { float v; int cnt; int pad[30]; };
__device__ Line g_line[NLINE];
__device__ int  g_master;

__global__ __launch_bounds__(256) void OrdinalLoss_main_kernel(
    const float* __restrict__ pred, const int* __restrict__ tgt,
    float* __restrict__ out, int nrows)
{
    const int tid    = blockIdx.x * blockDim.x + threadIdx.x;
    const int lane   = threadIdx.x & 63;
    const int g      = lane >> 4;        // row within 4-row pack
    const int li     = lane & 15;        // lane within 16-lane row group
    const int wave   = tid >> 6;
    const int nwaves = (gridDim.x * blockDim.x) >> 6;

    float acc = 0.0f;

    // per-lane column constants: col(k) = li*4 + (k>>2)*64 + (k&3)
    const float j0 = (float)(li * 4);
    float c[16], c2[16];
    #pragma unroll
    for (int k = 0; k < 16; ++k) {
        const float col = j0 + (float)((k >> 2) * 64 + (k & 3));
        c[k]  = col;
        c2[k] = col * col;
    }

    const int npacks = nrows >> 2;
    for (int pack = wave; pack < npacks; pack += nwaves) {
        const int row = pack * 4 + g;
        const float* rp = pred + (size_t)row * NCLS + li * 4;

        // NON-TEMPORAL streaming loads: data is read exactly once per pass;
        // nt bit steers it to the streaming path instead of the slow L3-hit path
        const nt_f4 a0 = __builtin_nontemporal_load(
                             reinterpret_cast<const nt_f4*>(rp));
        const nt_f4 a1 = __builtin_nontemporal_load(
                             reinterpret_cast<const nt_f4*>(rp + 64));
        const nt_f4 a2 = __builtin_nontemporal_load(
                             reinterpret_cast<const nt_f4*>(rp + 128));
        const nt_f4 a3 = __builtin_nontemporal_load(
                             reinterpret_cast<const nt_f4*>(rp + 192));
        const int    t  = tgt[row];          // 16-lane broadcast, 1 line/wave

        // moments: s0=sum e, s1=sum e*j, s2=sum e*j^2 — independent of t
        float s0 = 0.0f, s1 = 0.0f, s2 = 0.0f;
        #define TERM(PV, K) { float e = __expf(PV); s0 += e;                \
                              s1 = fmaf(e, c[K],  s1);                      \
                              s2 = fmaf(e, c2[K], s2); }
        TERM(a0[0], 0)  TERM(a0[1], 1)  TERM(a0[2], 2)  TERM(a0[3], 3)
        TERM(a1[0], 4)  TERM(a1[1], 5)  TERM(a1[2], 6)  TERM(a1[3], 7)
        TERM(a2[0], 8)  TERM(a2[1], 9)  TERM(a2[2],10)  TERM(a2[3],11)
        TERM(a3[0],12)  TERM(a3[1],13)  TERM(a3[2],14)  TERM(a3[3],15)
        #undef TERM

        // in-register p[t] extraction: owning lane li==(t>>2)&15,
        // quad t>>6, component t&3. Static selects only (no runtime indexing).
        const int q  = t >> 6;
        const int r  = t & 3;
        const nt_f4 Q = (q == 0) ? a0 : (q == 1) ? a1 : (q == 2) ? a2 : a3;
        const float pv = (r == 0) ? Q[0] : (r == 1) ? Q[1] : (r == 2) ? Q[2] : Q[3];
        float pt = (li == ((t >> 2) & 15)) ? pv : 0.0f;

        // 16-lane reduce, 4 channels, masks 8/4/2/1 only
        #pragma unroll
        for (int m = 8; m; m >>= 1) {
            s0 += __shfl_xor(s0, m);
            s1 += __shfl_xor(s1, m);
            s2 += __shfl_xor(s2, m);
            pt += __shfl_xor(pt, m);
        }
        if (li == 0) {
            const float tf = (float)t;
            // row loss = (log s0 - p_t) + (s2 - 2 t s1 + t^2 s0)/s0
            acc += __logf(s0) - pt
                 + (s2 - 2.0f * tf * s1 + tf * tf * s0) / s0;
        }
    }

    // ---- block reduce ----
    __shared__ float red[256];
    __shared__ int amLast;
    red[threadIdx.x] = acc;
    __syncthreads();
    float v = 0.0f;
    if (threadIdx.x < 64) {
        v = red[threadIdx.x] + red[threadIdx.x + 64] +
            red[threadIdx.x + 128] + red[threadIdx.x + 192];
        #pragma unroll
        for (int mask = 32; mask; mask >>= 1)
            v += __shfl_xor(v, mask);
    }

    // ---- fence-free fused finish (R6-proven) ----
    if (threadIdx.x == 0) {
        amLast = 0;
        const int ln = blockIdx.x & (NLINE - 1);
        float old = atomicAdd(&g_line[ln].v, v * (1.0f / (float)NROWS));
        asm volatile("" :: "v"(old));        // force vmcnt wait: add completed
        if (atomicAdd(&g_line[ln].cnt, 1) == BPL - 1) {
            if (atomicAdd(&g_master, 1) == NLINE - 1)
                amLast = 1;                  // all lines complete
        }
    }
    __syncthreads();
    if (amLast) {
        if (threadIdx.x < NLINE) {
            float r = __hip_atomic_load(&g_line[threadIdx.x].v,
                                        __ATOMIC_RELAXED, __HIP_MEMORY_SCOPE_AGENT);
            #pragma unroll
            for (int mask = 32; mask; mask >>= 1)
                r += __shfl_xor(r, mask);
            if (threadIdx.x == 0)
                out[0] = r;
            __hip_atomic_store(&g_line[threadIdx.x].v, 0.0f,
                               __ATOMIC_RELAXED, __HIP_MEMORY_SCOPE_AGENT);
            __hip_atomic_store(&g_line[threadIdx.x].cnt, 0,
                               __ATOMIC_RELAXED, __HIP_MEMORY_SCOPE_AGENT);
            if (threadIdx.x == 0)
                __hip_atomic_store(&g_master, 0,
                                   __ATOMIC_RELAXED, __HIP_MEMORY_SCOPE_AGENT);
        }
    }
}

extern "C" void kernel_launch(void* const* d_in, const int* in_sizes, int n_in,
                              void* d_out, int out_size, void* d_ws, size_t ws_size,
                              hipStream_t stream) {
    const float* pred = (const float*)d_in[0];
    const int*   tgt  = (const int*)d_in[1];
    float*       out  = (float*)d_out;
    const int nrows   = in_sizes[1];   // 65536 targets

    OrdinalLoss_main_kernel<<<NBLK, 256, 0, stream>>>(pred, tgt, out, nrows);
}